// Round 1
// baseline (772.650 us; speedup 1.0000x reference)
//
#include <hip/hip_runtime.h>
#include <math.h>

#define NQ    20000
#define NV    19560
#define EMBED 256
#define NHEAD 4
#define DH    64
#define NLVL  4
#define NPTS  8
#define DEPTHD 64

// level geometry (hardcoded from SHAPES)
__device__ __constant__ int c_lvl_w[4] = {160, 80, 40, 20};
__device__ __constant__ int c_lvl_h[4] = {92, 46, 23, 12};
__device__ __constant__ int c_lvl_s[4] = {0, 14720, 18400, 19320};

// ---------------------------------------------------------------------------
// fp32 tiled GEMM: C[m,n] = sum_k A[m,k]*B[k,n] + bias[n]
// BM=BN=128, BK=16, 256 threads, 8x8 microtile per thread.
// A: [M,K] row-major (K=256). B: [K,N] row-major. C row stride = ldc.
// ---------------------------------------------------------------------------
__global__ __launch_bounds__(256) void gemm_bias_f32(
    const float* __restrict__ A, const float* __restrict__ B,
    const float* __restrict__ bias, float* __restrict__ C,
    int M, int N, int K, int ldc)
{
    constexpr int BM = 128, BN = 128, BK = 16;
    __shared__ float As[BK][BM + 4];   // transposed A tile, rows 16B-aligned
    __shared__ float Bs[BK][BN + 4];

    const int tid  = threadIdx.x;
    const int tr   = tid >> 4;   // 0..15
    const int tc   = tid & 15;   // 0..15
    const int brow = blockIdx.y * BM;
    const int bcol = blockIdx.x * BN;

    float acc[8][8] = {};

    for (int k0 = 0; k0 < K; k0 += BK) {
        // ---- A tile: 128 rows x 16 cols, float4 along K, transpose into As
        #pragma unroll
        for (int t = 0; t < 2; ++t) {
            int flat = tid + t * 256;        // 0..511
            int r    = flat >> 2;            // 0..127
            int c4   = (flat & 3) << 2;      // 0,4,8,12
            float4 av = make_float4(0.f, 0.f, 0.f, 0.f);
            if (brow + r < M)
                av = *reinterpret_cast<const float4*>(A + (size_t)(brow + r) * K + k0 + c4);
            As[c4 + 0][r] = av.x;
            As[c4 + 1][r] = av.y;
            As[c4 + 2][r] = av.z;
            As[c4 + 3][r] = av.w;
        }
        // ---- B tile: 16 rows x 128 cols, float4 direct
        #pragma unroll
        for (int t = 0; t < 2; ++t) {
            int flat = tid + t * 256;        // 0..511
            int r    = flat >> 5;            // 0..15
            int c4   = (flat & 31) << 2;     // 0..124
            float4 bv4 = *reinterpret_cast<const float4*>(B + (size_t)(k0 + r) * N + bcol + c4);
            *reinterpret_cast<float4*>(&Bs[r][c4]) = bv4;
        }
        __syncthreads();

        #pragma unroll
        for (int kk = 0; kk < BK; ++kk) {
            float a[8], b[8];
            *reinterpret_cast<float4*>(a)     = *reinterpret_cast<const float4*>(&As[kk][tr * 8]);
            *reinterpret_cast<float4*>(a + 4) = *reinterpret_cast<const float4*>(&As[kk][tr * 8 + 4]);
            *reinterpret_cast<float4*>(b)     = *reinterpret_cast<const float4*>(&Bs[kk][tc * 8]);
            *reinterpret_cast<float4*>(b + 4) = *reinterpret_cast<const float4*>(&Bs[kk][tc * 8 + 4]);
            #pragma unroll
            for (int i = 0; i < 8; ++i)
                #pragma unroll
                for (int j = 0; j < 8; ++j)
                    acc[i][j] = fmaf(a[i], b[j], acc[i][j]);
        }
        __syncthreads();
    }

    #pragma unroll
    for (int i = 0; i < 8; ++i) {
        int r = brow + tr * 8 + i;
        if (r >= M) continue;
        #pragma unroll
        for (int j = 0; j < 8; j += 4) {
            int c = bcol + tc * 8 + j;
            float4 o;
            o.x = acc[i][j + 0] + bias[c + 0];
            o.y = acc[i][j + 1] + bias[c + 1];
            o.z = acc[i][j + 2] + bias[c + 2];
            o.w = acc[i][j + 3] + bias[c + 3];
            *reinterpret_cast<float4*>(C + (size_t)r * ldc + c) = o;
        }
    }
}

// ---------------------------------------------------------------------------
// Sampling kernel: 1 block per query, 1 wave (64 lanes) per head.
// lane = channel d in [0,64). qproj row layout: [0:256) off_uv, [256:384) off_d,
// [384:512) attn logits.
// ---------------------------------------------------------------------------
__global__ __launch_bounds__(256) void deform_sample(
    const float* __restrict__ qproj,   // [NQ, 512]
    const float* __restrict__ vproj,   // [NV, 256]  (n, h*64+d)
    const float* __restrict__ ddist,   // [NV, 64]
    const float* __restrict__ refpts,  // [NQ, 4, 3]
    float* __restrict__ out)           // [NQ, 256]
{
    const int q    = blockIdx.x;
    const int h    = threadIdx.x >> 6;
    const int lane = threadIdx.x & 63;

    __shared__ float attn_s[NHEAD][32];

    const float* qrow = qproj + (size_t)q * 512;

    // ---- softmax over 32 logits (both 32-lane halves do identical work)
    float logit = qrow[384 + h * 32 + (lane & 31)];
    float m = logit;
    #pragma unroll
    for (int o = 16; o; o >>= 1) m = fmaxf(m, __shfl_xor(m, o));
    float e = __expf(logit - m);
    float s = e;
    #pragma unroll
    for (int o = 16; o; o >>= 1) s += __shfl_xor(s, o);
    if (lane < 32) attn_s[h][lane] = e / s;
    // attn_s[h] written & read only by this wave; wave-internal LDS dep is
    // handled by compiler-inserted lgkmcnt waits.

    // ---- reference points (4 z-anchors), uniform loads
    float rx[4], ry[4], rz[4];
    #pragma unroll
    for (int i = 0; i < 4; ++i) {
        rx[i] = refpts[(q * 4 + i) * 3 + 0];
        ry[i] = refpts[(q * 4 + i) * 3 + 1];
        rz[i] = refpts[(q * 4 + i) * 3 + 2];
    }

    float acc = 0.f;

    #pragma unroll
    for (int l = 0; l < NLVL; ++l) {
        const int   Wl  = c_lvl_w[l];
        const int   Hl  = c_lvl_h[l];
        const float fWl = (float)Wl, fHl = (float)Hl;
        const float* vl = vproj + (size_t)c_lvl_s[l] * 256 + h * 64 + lane;
        const float* dl = ddist + (size_t)c_lvl_s[l] * 64;

        #pragma unroll
        for (int p = 0; p < NPTS; ++p) {
            const int zi   = p & 3;
            const int oidx = (h * NLVL + l) * NPTS + p;
            float ox = qrow[oidx * 2 + 0];
            float oy = qrow[oidx * 2 + 1];
            float od = qrow[256 + oidx];

            float x = fmaf(rx[zi], fWl, ox - 0.5f);
            float y = fmaf(ry[zi], fHl, oy - 0.5f);
            float z = fmaf(rz[zi], 64.f, od - 0.5f);

            float x0f = floorf(x), y0f = floorf(y), z0f = floorf(z);
            float fx = x - x0f, fy = y - y0f, fz = z - z0f;
            int x0 = (int)x0f, y0 = (int)y0f, z0 = (int)z0f;

            int z0c = min(max(z0, 0), DEPTHD - 1);
            int z1c = min(max(z0 + 1, 0), DEPTHD - 1);
            float wz0 = (z0 >= 0 && z0 <= DEPTHD - 1) ? (1.f - fz) : 0.f;
            float wz1 = (z0 + 1 >= 0 && z0 + 1 <= DEPTHD - 1) ? fz : 0.f;

            float aw = attn_s[h][l * NPTS + p];

            #pragma unroll
            for (int cy = 0; cy < 2; ++cy) {
                int   yi = y0 + cy;
                float wy = cy ? fy : (1.f - fy);
                bool  vy = (yi >= 0 && yi < Hl);
                int   yc = min(max(yi, 0), Hl - 1);
                #pragma unroll
                for (int cx = 0; cx < 2; ++cx) {
                    int   xi = x0 + cx;
                    float wx = cx ? fx : (1.f - fx);
                    bool  vx = (xi >= 0 && xi < Wl);
                    float wuv = (vx && vy) ? wx * wy : 0.f;
                    if (wuv != 0.f) {              // wave-uniform branch
                        int xc  = min(max(xi, 0), Wl - 1);
                        int idx = yc * Wl + xc;
                        const float* dptr = dl + (size_t)idx * 64;
                        float dscore = wz0 * dptr[z0c] + wz1 * dptr[z1c];
                        float coef   = aw * wuv * dscore;
                        acc = fmaf(coef, vl[(size_t)idx * 256], acc);
                    }
                }
            }
        }
    }

    out[(size_t)q * 256 + h * 64 + lane] = acc;
}

// ---------------------------------------------------------------------------
extern "C" void kernel_launch(void* const* d_in, const int* in_sizes, int n_in,
                              void* d_out, int out_size, void* d_ws, size_t ws_size,
                              hipStream_t stream)
{
    const float* query  = (const float*)d_in[0];   // [1,20000,256]
    const float* value  = (const float*)d_in[1];   // [1,19560,256]
    const float* ddist  = (const float*)d_in[2];   // [1,19560,64]
    const float* refpts = (const float*)d_in[3];   // [1,20000,4,3]
    // d_in[4] spatial_shapes, d_in[5] level_start_index: hardcoded constants
    const float* Wv  = (const float*)d_in[6];
    const float* bv  = (const float*)d_in[7];
    const float* Wo  = (const float*)d_in[8];
    const float* bo  = (const float*)d_in[9];
    const float* Wod = (const float*)d_in[10];
    const float* bod = (const float*)d_in[11];
    const float* Wa  = (const float*)d_in[12];
    const float* ba  = (const float*)d_in[13];
    float* out = (float*)d_out;

    float* vbuf = (float*)d_ws;                      // [NV, 256]
    float* qbuf = vbuf + (size_t)NV * 256;           // [NQ, 512]

    dim3 blk(256);

    // v projection: [NV,256] = value @ Wv + bv
    gemm_bias_f32<<<dim3(2, (NV + 127) / 128), blk, 0, stream>>>(
        value, Wv, bv, vbuf, NV, 256, 256, 256);

    // query projections into qbuf rows of 512: [Wo(256) | Wod(128) | Wa(128)]
    gemm_bias_f32<<<dim3(2, (NQ + 127) / 128), blk, 0, stream>>>(
        query, Wo, bo, qbuf, NQ, 256, 256, 512);
    gemm_bias_f32<<<dim3(1, (NQ + 127) / 128), blk, 0, stream>>>(
        query, Wod, bod, qbuf + 256, NQ, 128, 256, 512);
    gemm_bias_f32<<<dim3(1, (NQ + 127) / 128), blk, 0, stream>>>(
        query, Wa, ba, qbuf + 384, NQ, 128, 256, 512);

    // sampling + attention-weighted accumulation
    deform_sample<<<dim3(NQ), blk, 0, stream>>>(qbuf, vbuf, ddist, refpts, out);
}

// Round 2
// 329.187 us; speedup vs baseline: 2.3471x; 2.3471x over previous
//
#include <hip/hip_runtime.h>
#include <math.h>

#define NQ    20000
#define NV    19560
#define EMBED 256
#define NHEAD 4
#define DH    64
#define NLVL  4
#define NPTS  8
#define DEPTHD 64

// ---------------------------------------------------------------------------
// fp32 tiled GEMM: C[m,n] = sum_k A[m,k]*B[k,n] + bias[n]
// BM=BN=128, BK=16, 256 threads, 8x8 microtile per thread.
// ---------------------------------------------------------------------------
__global__ __launch_bounds__(256) void gemm_bias_f32(
    const float* __restrict__ A, const float* __restrict__ B,
    const float* __restrict__ bias, float* __restrict__ C,
    int M, int N, int K, int ldc)
{
    constexpr int BM = 128, BN = 128, BK = 16;
    __shared__ float As[BK][BM + 4];
    __shared__ float Bs[BK][BN + 4];

    const int tid  = threadIdx.x;
    const int tr   = tid >> 4;
    const int tc   = tid & 15;
    const int brow = blockIdx.y * BM;
    const int bcol = blockIdx.x * BN;

    float acc[8][8] = {};

    for (int k0 = 0; k0 < K; k0 += BK) {
        #pragma unroll
        for (int t = 0; t < 2; ++t) {
            int flat = tid + t * 256;
            int r    = flat >> 2;
            int c4   = (flat & 3) << 2;
            float4 av = make_float4(0.f, 0.f, 0.f, 0.f);
            if (brow + r < M)
                av = *reinterpret_cast<const float4*>(A + (size_t)(brow + r) * K + k0 + c4);
            As[c4 + 0][r] = av.x;
            As[c4 + 1][r] = av.y;
            As[c4 + 2][r] = av.z;
            As[c4 + 3][r] = av.w;
        }
        #pragma unroll
        for (int t = 0; t < 2; ++t) {
            int flat = tid + t * 256;
            int r    = flat >> 5;
            int c4   = (flat & 31) << 2;
            float4 bv4 = *reinterpret_cast<const float4*>(B + (size_t)(k0 + r) * N + bcol + c4);
            *reinterpret_cast<float4*>(&Bs[r][c4]) = bv4;
        }
        __syncthreads();

        #pragma unroll
        for (int kk = 0; kk < BK; ++kk) {
            float a[8], b[8];
            *reinterpret_cast<float4*>(a)     = *reinterpret_cast<const float4*>(&As[kk][tr * 8]);
            *reinterpret_cast<float4*>(a + 4) = *reinterpret_cast<const float4*>(&As[kk][tr * 8 + 4]);
            *reinterpret_cast<float4*>(b)     = *reinterpret_cast<const float4*>(&Bs[kk][tc * 8]);
            *reinterpret_cast<float4*>(b + 4) = *reinterpret_cast<const float4*>(&Bs[kk][tc * 8 + 4]);
            #pragma unroll
            for (int i = 0; i < 8; ++i)
                #pragma unroll
                for (int j = 0; j < 8; ++j)
                    acc[i][j] = fmaf(a[i], b[j], acc[i][j]);
        }
        __syncthreads();
    }

    #pragma unroll
    for (int i = 0; i < 8; ++i) {
        int r = brow + tr * 8 + i;
        if (r >= M) continue;
        #pragma unroll
        for (int j = 0; j < 8; j += 4) {
            int c = bcol + tc * 8 + j;
            float4 o;
            o.x = acc[i][j + 0] + bias[c + 0];
            o.y = acc[i][j + 1] + bias[c + 1];
            o.z = acc[i][j + 2] + bias[c + 2];
            o.w = acc[i][j + 3] + bias[c + 3];
            *reinterpret_cast<float4*>(C + (size_t)r * ldc + c) = o;
        }
    }
}

// ---------------------------------------------------------------------------
// Fused query projection: one dispatch computes all 512 output columns.
// blockIdx.x = 0,1 -> Wo cols [0,128)/[128,256); 2 -> Wod; 3 -> Wa.
// Output row stride 512, col base = blockIdx.x*128.
// ---------------------------------------------------------------------------
__global__ __launch_bounds__(256) void gemm_qproj_f32(
    const float* __restrict__ A,
    const float* __restrict__ Wo,  const float* __restrict__ bo,
    const float* __restrict__ Wod, const float* __restrict__ bod,
    const float* __restrict__ Wa,  const float* __restrict__ ba,
    float* __restrict__ C, int M)
{
    constexpr int BM = 128, BN = 128, BK = 16, K = 256;
    __shared__ float As[BK][BM + 4];
    __shared__ float Bs[BK][BN + 4];

    const float* B;  const float* bias;  int ldb, bcolB;
    switch (blockIdx.x) {
        case 0:  B = Wo;  bias = bo;  ldb = 256; bcolB = 0;   break;
        case 1:  B = Wo;  bias = bo;  ldb = 256; bcolB = 128; break;
        case 2:  B = Wod; bias = bod; ldb = 128; bcolB = 0;   break;
        default: B = Wa;  bias = ba;  ldb = 128; bcolB = 0;   break;
    }

    const int tid  = threadIdx.x;
    const int tr   = tid >> 4;
    const int tc   = tid & 15;
    const int brow = blockIdx.y * BM;
    const int ccol = blockIdx.x * BN;   // column base in C (row stride 512)

    float acc[8][8] = {};

    for (int k0 = 0; k0 < K; k0 += BK) {
        #pragma unroll
        for (int t = 0; t < 2; ++t) {
            int flat = tid + t * 256;
            int r    = flat >> 2;
            int c4   = (flat & 3) << 2;
            float4 av = make_float4(0.f, 0.f, 0.f, 0.f);
            if (brow + r < M)
                av = *reinterpret_cast<const float4*>(A + (size_t)(brow + r) * K + k0 + c4);
            As[c4 + 0][r] = av.x;
            As[c4 + 1][r] = av.y;
            As[c4 + 2][r] = av.z;
            As[c4 + 3][r] = av.w;
        }
        #pragma unroll
        for (int t = 0; t < 2; ++t) {
            int flat = tid + t * 256;
            int r    = flat >> 5;
            int c4   = (flat & 31) << 2;
            float4 bv4 = *reinterpret_cast<const float4*>(B + (size_t)(k0 + r) * ldb + bcolB + c4);
            *reinterpret_cast<float4*>(&Bs[r][c4]) = bv4;
        }
        __syncthreads();

        #pragma unroll
        for (int kk = 0; kk < BK; ++kk) {
            float a[8], b[8];
            *reinterpret_cast<float4*>(a)     = *reinterpret_cast<const float4*>(&As[kk][tr * 8]);
            *reinterpret_cast<float4*>(a + 4) = *reinterpret_cast<const float4*>(&As[kk][tr * 8 + 4]);
            *reinterpret_cast<float4*>(b)     = *reinterpret_cast<const float4*>(&Bs[kk][tc * 8]);
            *reinterpret_cast<float4*>(b + 4) = *reinterpret_cast<const float4*>(&Bs[kk][tc * 8 + 4]);
            #pragma unroll
            for (int i = 0; i < 8; ++i)
                #pragma unroll
                for (int j = 0; j < 8; ++j)
                    acc[i][j] = fmaf(a[i], b[j], acc[i][j]);
        }
        __syncthreads();
    }

    #pragma unroll
    for (int i = 0; i < 8; ++i) {
        int r = brow + tr * 8 + i;
        if (r >= M) continue;
        #pragma unroll
        for (int j = 0; j < 8; j += 4) {
            int c = tc * 8 + j;          // column within this 128-tile
            float4 o;
            o.x = acc[i][j + 0] + bias[bcolB + c + 0];
            o.y = acc[i][j + 1] + bias[bcolB + c + 1];
            o.z = acc[i][j + 2] + bias[bcolB + c + 2];
            o.w = acc[i][j + 3] + bias[bcolB + c + 3];
            *reinterpret_cast<float4*>(C + (size_t)r * 512 + ccol + c) = o;
        }
    }
}

// ---------------------------------------------------------------------------
// Sampling kernel, restructured:
//  Phase A (lane = point): 32 lanes compute softmax + trilinear weights for
//    one point each, in parallel; write 4 (coef,row) pairs per point to LDS.
//  Phase B (lane = channel): 128-iter uniform-read + gather-fma loop.
// ---------------------------------------------------------------------------
__global__ __launch_bounds__(256) void deform_sample(
    const float* __restrict__ qproj,   // [NQ, 512]  [off_uv(256)|off_d(128)|attn(128)]
    const float* __restrict__ vproj,   // [NV, 256]  (n, h*64+d)
    const float* __restrict__ ddist,   // [NV, 64]
    const float* __restrict__ refpts,  // [NQ, 4, 3]
    float* __restrict__ out)           // [NQ, 256]
{
    const int q    = blockIdx.x;
    const int h    = threadIdx.x >> 6;
    const int lane = threadIdx.x & 63;
    const int j    = lane & 31;        // point index l*8+p (both halves duplicate)

    __shared__ float2 sm[NHEAD][128];  // (coef, row-as-float-bits) per corner

    const float* qrow = qproj + (size_t)q * 512;

    // ---- softmax over 32 logits (xor offsets <32 stay within each half)
    float logit = qrow[384 + h * 32 + j];
    float m = logit;
    #pragma unroll
    for (int o = 16; o; o >>= 1) m = fmaxf(m, __shfl_xor(m, o));
    float e = __expf(logit - m);
    float s = e;
    #pragma unroll
    for (int o = 16; o; o >>= 1) s += __shfl_xor(s, o);
    const float aw = e / s;

    // ---- per-point trilinear setup
    const int l  = j >> 3;
    const int p  = j & 7;
    const int zi = p & 3;
    const int   Wl  = 160 >> l;                                   // 160,80,40,20
    const int   Hl  = (l == 0) ? 92 : (l == 1) ? 46 : (l == 2) ? 23 : 12;
    const int   st  = (l == 0) ? 0  : (l == 1) ? 14720 : (l == 2) ? 18400 : 19320;

    const int oidx = (h * 4 + l) * 8 + p;
    const float ox = qrow[oidx * 2 + 0];
    const float oy = qrow[oidx * 2 + 1];
    const float od = qrow[256 + oidx];
    const float rx = refpts[(q * 4 + zi) * 3 + 0];
    const float ry = refpts[(q * 4 + zi) * 3 + 1];
    const float rz = refpts[(q * 4 + zi) * 3 + 2];

    const float x = fmaf(rx, (float)Wl, ox - 0.5f);
    const float y = fmaf(ry, (float)Hl, oy - 0.5f);
    const float z = fmaf(rz, 64.0f,     od - 0.5f);
    const float x0f = floorf(x), y0f = floorf(y), z0f = floorf(z);
    const float fx = x - x0f, fy = y - y0f, fz = z - z0f;
    const int x0 = (int)x0f, y0 = (int)y0f, z0 = (int)z0f;

    const int z0c = min(max(z0, 0), DEPTHD - 1);
    const int z1c = min(max(z0 + 1, 0), DEPTHD - 1);
    const float wz0 = (z0 >= 0 && z0 <= DEPTHD - 1) ? (1.f - fz) : 0.f;
    const float wz1 = (z0 >= -1 && z0 <= DEPTHD - 2) ? fz : 0.f;

    #pragma unroll
    for (int c = 0; c < 4; ++c) {
        const int   cy = c >> 1, cx = c & 1;
        const int   yi = y0 + cy, xi = x0 + cx;
        const float wy = cy ? fy : (1.f - fy);
        const float wx = cx ? fx : (1.f - fx);
        const bool  valid = (xi >= 0) & (xi < Wl) & (yi >= 0) & (yi < Hl);
        const int   yc = min(max(yi, 0), Hl - 1);
        const int   xc = min(max(xi, 0), Wl - 1);
        const int   row = st + yc * Wl + xc;           // valid v-row always
        const float* dptr = ddist + (size_t)row * 64;
        const float dscore = wz0 * dptr[z0c] + wz1 * dptr[z1c];
        const float coef = valid ? (aw * wx * wy * dscore) : 0.f;
        if (lane < 32)
            sm[h][j * 4 + c] = make_float2(coef, __int_as_float(row));
    }
    __syncthreads();

    // ---- phase B: gather-accumulate (lane = channel)
    const int voff = h * 64 + lane;
    const float* __restrict__ vbase = vproj + voff;
    float acc = 0.f;
    #pragma unroll 8
    for (int c = 0; c < 128; ++c) {
        const float2 wi = sm[h][c];
        const int row = __float_as_int(wi.y);
        acc = fmaf(wi.x, vbase[row * 256], acc);
    }
    out[(size_t)q * 256 + voff] = acc;
}

// ---------------------------------------------------------------------------
extern "C" void kernel_launch(void* const* d_in, const int* in_sizes, int n_in,
                              void* d_out, int out_size, void* d_ws, size_t ws_size,
                              hipStream_t stream)
{
    const float* query  = (const float*)d_in[0];
    const float* value  = (const float*)d_in[1];
    const float* ddist  = (const float*)d_in[2];
    const float* refpts = (const float*)d_in[3];
    const float* Wv  = (const float*)d_in[6];
    const float* bv  = (const float*)d_in[7];
    const float* Wo  = (const float*)d_in[8];
    const float* bo  = (const float*)d_in[9];
    const float* Wod = (const float*)d_in[10];
    const float* bod = (const float*)d_in[11];
    const float* Wa  = (const float*)d_in[12];
    const float* ba  = (const float*)d_in[13];
    float* out = (float*)d_out;

    float* vbuf = (float*)d_ws;                      // [NV, 256]
    float* qbuf = vbuf + (size_t)NV * 256;           // [NQ, 512]

    dim3 blk(256);

    gemm_bias_f32<<<dim3(2, (NV + 127) / 128), blk, 0, stream>>>(
        value, Wv, bv, vbuf, NV, 256, 256, 256);

    gemm_qproj_f32<<<dim3(4, (NQ + 127) / 128), blk, 0, stream>>>(
        query, Wo, bo, Wod, bod, Wa, ba, qbuf, NQ);

    deform_sample<<<dim3(NQ), blk, 0, stream>>>(qbuf, vbuf, ddist, refpts, out);
}

// Round 3
// 226.841 us; speedup vs baseline: 3.4061x; 1.4512x over previous
//
#include <hip/hip_runtime.h>
#include <math.h>

#define NQ    20000
#define NV    19560
#define NHEAD 4
#define DEPTHD 64

typedef __attribute__((ext_vector_type(8))) short short8;
typedef __attribute__((ext_vector_type(4))) float f32x4;

__device__ __forceinline__ ushort f2bf(float f) {
    uint32_t u = __float_as_uint(f);
    uint32_t r = (u + 0x7FFFu + ((u >> 16) & 1u)) >> 16;
    return (ushort)r;
}
__device__ __forceinline__ float bf2f(ushort u) {
    return __uint_as_float(((uint32_t)u) << 16);
}

// ---------------------------------------------------------------------------
// Weight prep: WvT[n][k]=bf16(Wv[k][n]); WqT[n][k]=bf16(concat cols of Wo|Wod|Wa);
// bq = [bo|bod|ba] fp32.
// ---------------------------------------------------------------------------
__global__ __launch_bounds__(256) void prep_weights(
    const float* __restrict__ Wv, const float* __restrict__ Wo,
    const float* __restrict__ Wod, const float* __restrict__ Wa,
    const float* __restrict__ bo, const float* __restrict__ bod,
    const float* __restrict__ ba,
    ushort* __restrict__ WvT, ushort* __restrict__ WqT, float* __restrict__ bq)
{
    const int b = blockIdx.x;
    const int k = threadIdx.x;           // 0..255
    if (b < 256) {                       // WvT row n=b
        WvT[b * 256 + k] = f2bf(Wv[k * 256 + b]);
    } else if (b < 768) {                // WqT row n=b-256
        const int n = b - 256;
        float w;
        if (n < 256)      w = Wo [k * 256 + n];
        else if (n < 384) w = Wod[k * 128 + (n - 256)];
        else              w = Wa [k * 128 + (n - 384)];
        WqT[n * 256 + k] = f2bf(w);
    } else {                             // bias concat, 512 entries
        for (int i = k; i < 512; i += 256) {
            float v;
            if (i < 256)      v = bo[i];
            else if (i < 384) v = bod[i - 256];
            else              v = ba[i - 384];
            bq[i] = v;
        }
    }
}

// ---------------------------------------------------------------------------
// bf16 MFMA GEMM: C = A(fp32,[M][256]) x BT(bf16,[N][256])^T + bias.
// 128x128 tile, BK=32, 4 waves (2x2), each wave 64x64 via 16x16x32 MFMA.
// BF16_OUT: write bf16 (row stride ldc elems), else fp32.
// ---------------------------------------------------------------------------
template<bool BF16_OUT>
__global__ __launch_bounds__(256) void gemm_mfma_bf16(
    const float* __restrict__ A, const ushort* __restrict__ BT,
    const float* __restrict__ bias, void* __restrict__ Cout,
    int M, int ldc)
{
    constexpr int K = 256, BK = 32;
    __shared__ ushort Asb[128][40];   // +8 pad: 2-way-max bank aliasing (free)
    __shared__ ushort Bsb[128][40];

    const int tid  = threadIdx.x;
    const int lane = tid & 63;
    const int wave = tid >> 6;
    const int wm   = wave >> 1;       // 0..1
    const int wn   = wave & 1;        // 0..1
    const int brow = blockIdx.y * 128;
    const int bcol = blockIdx.x * 128;
    const int l15  = lane & 15;
    const int kg   = lane >> 4;       // k-chunk 0..3

    f32x4 acc[4][4] = {};

    const int rA    = tid >> 1;       // staging row 0..127
    const int partA = tid & 1;        // k-half 0/1

    for (int k0 = 0; k0 < K; k0 += BK) {
        // ---- stage A: fp32 -> bf16, 16 elems/thread
        {
            ushort tmp[16];
            if (brow + rA < M) {
                const float* ap = A + (size_t)(brow + rA) * K + k0 + partA * 16;
                #pragma unroll
                for (int i = 0; i < 4; ++i) {
                    float4 v = *reinterpret_cast<const float4*>(ap + i * 4);
                    tmp[i * 4 + 0] = f2bf(v.x);
                    tmp[i * 4 + 1] = f2bf(v.y);
                    tmp[i * 4 + 2] = f2bf(v.z);
                    tmp[i * 4 + 3] = f2bf(v.w);
                }
            } else {
                #pragma unroll
                for (int i = 0; i < 16; ++i) tmp[i] = 0;
            }
            *reinterpret_cast<uint4*>(&Asb[rA][partA * 16 + 0]) = *reinterpret_cast<uint4*>(tmp);
            *reinterpret_cast<uint4*>(&Asb[rA][partA * 16 + 8]) = *reinterpret_cast<uint4*>(tmp + 8);
        }
        // ---- stage BT: bf16 direct, 16B/chunk
        #pragma unroll
        for (int i = 0; i < 2; ++i) {
            int f  = tid + i * 256;
            int n  = f >> 2;
            int c8 = (f & 3) * 8;
            uint4 v = *reinterpret_cast<const uint4*>(BT + (size_t)(bcol + n) * K + k0 + c8);
            *reinterpret_cast<uint4*>(&Bsb[n][c8]) = v;
        }
        __syncthreads();

        short8 af[4], bfv[4];
        #pragma unroll
        for (int mf = 0; mf < 4; ++mf)
            af[mf] = *reinterpret_cast<const short8*>(&Asb[wm * 64 + mf * 16 + l15][kg * 8]);
        #pragma unroll
        for (int nf = 0; nf < 4; ++nf)
            bfv[nf] = *reinterpret_cast<const short8*>(&Bsb[wn * 64 + nf * 16 + l15][kg * 8]);
        #pragma unroll
        for (int mf = 0; mf < 4; ++mf)
            #pragma unroll
            for (int nf = 0; nf < 4; ++nf)
                acc[mf][nf] = __builtin_amdgcn_mfma_f32_16x16x32_bf16(af[mf], bfv[nf], acc[mf][nf], 0, 0, 0);
        __syncthreads();
    }

    // ---- epilogue: C/D layout col=lane&15, row=(lane>>4)*4+reg
    #pragma unroll
    for (int mf = 0; mf < 4; ++mf) {
        #pragma unroll
        for (int reg = 0; reg < 4; ++reg) {
            int row = brow + wm * 64 + mf * 16 + kg * 4 + reg;
            if (row >= M) continue;
            #pragma unroll
            for (int nf = 0; nf < 4; ++nf) {
                int col = bcol + wn * 64 + nf * 16 + l15;
                float v = acc[mf][nf][reg] + bias[col];
                if (BF16_OUT)
                    ((ushort*)Cout)[(size_t)row * ldc + col] = f2bf(v);
                else
                    ((float*)Cout)[(size_t)row * ldc + col] = v;
            }
        }
    }
}

// ---------------------------------------------------------------------------
// Sampler. Phase A (lane=point): softmax + trilinear weights -> LDS (coef, byteoff).
// Phase B (lane=channel): 128x {uniform LDS read, bf16 gather, fma}.
// ---------------------------------------------------------------------------
__global__ __launch_bounds__(256) void deform_sample(
    const float* __restrict__ qproj,   // [NQ,512] [off_uv(256)|off_d(128)|attn(128)]
    const ushort* __restrict__ vproj,  // [NV,256] bf16
    const float* __restrict__ ddist,   // [NV,64]
    const float* __restrict__ refpts,  // [NQ,4,3]
    float* __restrict__ out)           // [NQ,256]
{
    const int q    = blockIdx.x;
    const int h    = threadIdx.x >> 6;
    const int lane = threadIdx.x & 63;
    const int j    = lane & 31;

    __shared__ float2 sm[NHEAD][128];  // [h][corner*32 + point] = (coef, byteoff)

    const float* qrow = qproj + (size_t)q * 512;

    // softmax over 32 logits
    float logit = qrow[384 + h * 32 + j];
    float m = logit;
    #pragma unroll
    for (int o = 16; o; o >>= 1) m = fmaxf(m, __shfl_xor(m, o));
    float e = __expf(logit - m);
    float s = e;
    #pragma unroll
    for (int o = 16; o; o >>= 1) s += __shfl_xor(s, o);
    const float aw = e / s;

    const int l  = j >> 3;
    const int p  = j & 7;
    const int zi = p & 3;
    const int Wl = 160 >> l;
    const int Hl = (l == 0) ? 92 : (l == 1) ? 46 : (l == 2) ? 23 : 12;
    const int st = (l == 0) ? 0  : (l == 1) ? 14720 : (l == 2) ? 18400 : 19320;

    const int oidx = (h * 4 + l) * 8 + p;
    const float ox = qrow[oidx * 2 + 0];
    const float oy = qrow[oidx * 2 + 1];
    const float od = qrow[256 + oidx];
    const float rx = refpts[(q * 4 + zi) * 3 + 0];
    const float ry = refpts[(q * 4 + zi) * 3 + 1];
    const float rz = refpts[(q * 4 + zi) * 3 + 2];

    const float x = fmaf(rx, (float)Wl, ox - 0.5f);
    const float y = fmaf(ry, (float)Hl, oy - 0.5f);
    const float z = fmaf(rz, 64.0f,     od - 0.5f);
    const float x0f = floorf(x), y0f = floorf(y), z0f = floorf(z);
    const float fx = x - x0f, fy = y - y0f, fz = z - z0f;
    const int x0 = (int)x0f, y0 = (int)y0f, z0 = (int)z0f;

    const int z0c = min(max(z0, 0), DEPTHD - 1);
    const int z1c = min(max(z0 + 1, 0), DEPTHD - 1);
    const float wz0 = (z0 >= 0 && z0 <= DEPTHD - 1) ? (1.f - fz) : 0.f;
    const float wz1 = (z0 >= -1 && z0 <= DEPTHD - 2) ? fz : 0.f;

    #pragma unroll
    for (int c = 0; c < 4; ++c) {
        const int   cy = c >> 1, cx = c & 1;
        const int   yi = y0 + cy, xi = x0 + cx;
        const float wy = cy ? fy : (1.f - fy);
        const float wx = cx ? fx : (1.f - fx);
        const bool  valid = (xi >= 0) & (xi < Wl) & (yi >= 0) & (yi < Hl);
        const int   yc = min(max(yi, 0), Hl - 1);
        const int   xc = min(max(xi, 0), Wl - 1);
        const int   row = st + yc * Wl + xc;
        const float* dptr = ddist + (size_t)row * 64;
        const float dscore = wz0 * dptr[z0c] + wz1 * dptr[z1c];
        const float coef = valid ? (aw * wx * wy * dscore) : 0.f;
        if (lane < 32)
            sm[h][c * 32 + j] = make_float2(coef, __int_as_float(row * 512)); // byte off
    }
    __syncthreads();

    // phase B: lane = channel
    const uint32_t chb = (uint32_t)(h * 64 + lane) * 2u;  // channel byte offset
    const char* vb = (const char*)vproj;
    float a0 = 0.f, a1 = 0.f, a2 = 0.f, a3 = 0.f;
    const float2* smh = sm[h];
    #pragma unroll 8
    for (int c = 0; c < 128; c += 4) {
        float2 w0 = smh[c + 0], w1 = smh[c + 1], w2 = smh[c + 2], w3 = smh[c + 3];
        uint32_t o0 = (uint32_t)__float_as_int(w0.y) + chb;
        uint32_t o1 = (uint32_t)__float_as_int(w1.y) + chb;
        uint32_t o2 = (uint32_t)__float_as_int(w2.y) + chb;
        uint32_t o3 = (uint32_t)__float_as_int(w3.y) + chb;
        a0 = fmaf(w0.x, bf2f(*(const ushort*)(vb + o0)), a0);
        a1 = fmaf(w1.x, bf2f(*(const ushort*)(vb + o1)), a1);
        a2 = fmaf(w2.x, bf2f(*(const ushort*)(vb + o2)), a2);
        a3 = fmaf(w3.x, bf2f(*(const ushort*)(vb + o3)), a3);
    }
    out[(size_t)q * 256 + h * 64 + lane] = (a0 + a1) + (a2 + a3);
}

// ---------------------------------------------------------------------------
extern "C" void kernel_launch(void* const* d_in, const int* in_sizes, int n_in,
                              void* d_out, int out_size, void* d_ws, size_t ws_size,
                              hipStream_t stream)
{
    const float* query  = (const float*)d_in[0];
    const float* value  = (const float*)d_in[1];
    const float* ddist  = (const float*)d_in[2];
    const float* refpts = (const float*)d_in[3];
    const float* Wv  = (const float*)d_in[6];
    const float* bv  = (const float*)d_in[7];
    const float* Wo  = (const float*)d_in[8];
    const float* bo  = (const float*)d_in[9];
    const float* Wod = (const float*)d_in[10];
    const float* bod = (const float*)d_in[11];
    const float* Wa  = (const float*)d_in[12];
    const float* ba  = (const float*)d_in[13];
    float* out = (float*)d_out;

    char* ws = (char*)d_ws;
    ushort* vbuf = (ushort*)ws;                                   // NV*256 bf16 = 10,014,720 B
    float*  qbuf = (float*)(ws + 10014720);                       // NQ*512 f32  = 40,960,000 B
    ushort* WvT  = (ushort*)(ws + 10014720 + 40960000);           // 256*256*2
    ushort* WqT  = WvT + 256 * 256;                               // 512*256*2
    float*  bq   = (float*)(WqT + 512 * 256);                     // 512*4

    dim3 blk(256);

    prep_weights<<<dim3(769), blk, 0, stream>>>(Wv, Wo, Wod, Wa, bo, bod, ba, WvT, WqT, bq);

    // v projection -> bf16 vbuf [NV,256]
    gemm_mfma_bf16<true><<<dim3(2, (NV + 127) / 128), blk, 0, stream>>>(
        value, WvT, bv, vbuf, NV, 256);

    // query projections -> fp32 qbuf [NQ,512]
    gemm_mfma_bf16<false><<<dim3(4, (NQ + 127) / 128), blk, 0, stream>>>(
        query, WqT, bq, qbuf, NQ, 512);

    deform_sample<<<dim3(NQ), blk, 0, stream>>>(qbuf, vbuf, ddist, refpts, out);
}

// Round 4
// 168.680 us; speedup vs baseline: 4.5806x; 1.3448x over previous
//
#include <hip/hip_runtime.h>
#include <math.h>

#define NQ    20000
#define NV    19560
#define NHEAD 4
#define DEPTHD 64

typedef __attribute__((ext_vector_type(8))) short short8;
typedef __attribute__((ext_vector_type(4))) float f32x4;

__device__ __forceinline__ ushort f2bf(float f) {
    uint32_t u = __float_as_uint(f);
    uint32_t r = (u + 0x7FFFu + ((u >> 16) & 1u)) >> 16;
    return (ushort)r;
}
__device__ __forceinline__ float bf_lo(uint32_t d) { return __uint_as_float(d << 16); }
__device__ __forceinline__ float bf_hi(uint32_t d) { return __uint_as_float(d & 0xFFFF0000u); }

// ---------------------------------------------------------------------------
// Weight prep: WvT[n][k]=bf16(Wv[k][n]); WqT[n][k]=bf16(concat cols of Wo|Wod|Wa);
// bq = [bo|bod|ba] fp32.
// ---------------------------------------------------------------------------
__global__ __launch_bounds__(256) void prep_weights(
    const float* __restrict__ Wv, const float* __restrict__ Wo,
    const float* __restrict__ Wod, const float* __restrict__ Wa,
    const float* __restrict__ bo, const float* __restrict__ bod,
    const float* __restrict__ ba,
    ushort* __restrict__ WvT, ushort* __restrict__ WqT, float* __restrict__ bq)
{
    const int b = blockIdx.x;
    const int k = threadIdx.x;           // 0..255
    if (b < 256) {                       // WvT row n=b
        WvT[b * 256 + k] = f2bf(Wv[k * 256 + b]);
    } else if (b < 768) {                // WqT row n=b-256
        const int n = b - 256;
        float w;
        if (n < 256)      w = Wo [k * 256 + n];
        else if (n < 384) w = Wod[k * 128 + (n - 256)];
        else              w = Wa [k * 128 + (n - 384)];
        WqT[n * 256 + k] = f2bf(w);
    } else {                             // bias concat, 512 entries
        for (int i = k; i < 512; i += 256) {
            float v;
            if (i < 256)      v = bo[i];
            else if (i < 384) v = bod[i - 256];
            else              v = ba[i - 384];
            bq[i] = v;
        }
    }
}

// ---------------------------------------------------------------------------
// bf16 MFMA GEMM: C = A(fp32,[M][256]) x BT(bf16,[N][256])^T + bias.
// 128x128 tile, BK=32, 4 waves (2x2), each wave 64x64 via 16x16x32 MFMA.
// ---------------------------------------------------------------------------
template<bool BF16_OUT>
__global__ __launch_bounds__(256) void gemm_mfma_bf16(
    const float* __restrict__ A, const ushort* __restrict__ BT,
    const float* __restrict__ bias, void* __restrict__ Cout,
    int M, int ldc)
{
    constexpr int K = 256, BK = 32;
    __shared__ ushort Asb[128][40];
    __shared__ ushort Bsb[128][40];

    const int tid  = threadIdx.x;
    const int lane = tid & 63;
    const int wave = tid >> 6;
    const int wm   = wave >> 1;
    const int wn   = wave & 1;
    const int brow = blockIdx.y * 128;
    const int bcol = blockIdx.x * 128;
    const int l15  = lane & 15;
    const int kg   = lane >> 4;

    f32x4 acc[4][4] = {};

    const int rA    = tid >> 1;
    const int partA = tid & 1;

    for (int k0 = 0; k0 < K; k0 += BK) {
        {
            ushort tmp[16];
            if (brow + rA < M) {
                const float* ap = A + (size_t)(brow + rA) * K + k0 + partA * 16;
                #pragma unroll
                for (int i = 0; i < 4; ++i) {
                    float4 v = *reinterpret_cast<const float4*>(ap + i * 4);
                    tmp[i * 4 + 0] = f2bf(v.x);
                    tmp[i * 4 + 1] = f2bf(v.y);
                    tmp[i * 4 + 2] = f2bf(v.z);
                    tmp[i * 4 + 3] = f2bf(v.w);
                }
            } else {
                #pragma unroll
                for (int i = 0; i < 16; ++i) tmp[i] = 0;
            }
            *reinterpret_cast<uint4*>(&Asb[rA][partA * 16 + 0]) = *reinterpret_cast<uint4*>(tmp);
            *reinterpret_cast<uint4*>(&Asb[rA][partA * 16 + 8]) = *reinterpret_cast<uint4*>(tmp + 8);
        }
        #pragma unroll
        for (int i = 0; i < 2; ++i) {
            int f  = tid + i * 256;
            int n  = f >> 2;
            int c8 = (f & 3) * 8;
            uint4 v = *reinterpret_cast<const uint4*>(BT + (size_t)(bcol + n) * K + k0 + c8);
            *reinterpret_cast<uint4*>(&Bsb[n][c8]) = v;
        }
        __syncthreads();

        short8 af[4], bfv[4];
        #pragma unroll
        for (int mf = 0; mf < 4; ++mf)
            af[mf] = *reinterpret_cast<const short8*>(&Asb[wm * 64 + mf * 16 + l15][kg * 8]);
        #pragma unroll
        for (int nf = 0; nf < 4; ++nf)
            bfv[nf] = *reinterpret_cast<const short8*>(&Bsb[wn * 64 + nf * 16 + l15][kg * 8]);
        #pragma unroll
        for (int mf = 0; mf < 4; ++mf)
            #pragma unroll
            for (int nf = 0; nf < 4; ++nf)
                acc[mf][nf] = __builtin_amdgcn_mfma_f32_16x16x32_bf16(af[mf], bfv[nf], acc[mf][nf], 0, 0, 0);
        __syncthreads();
    }

    #pragma unroll
    for (int mf = 0; mf < 4; ++mf) {
        #pragma unroll
        for (int reg = 0; reg < 4; ++reg) {
            int row = brow + wm * 64 + mf * 16 + kg * 4 + reg;
            if (row >= M) continue;
            #pragma unroll
            for (int nf = 0; nf < 4; ++nf) {
                int col = bcol + wn * 64 + nf * 16 + l15;
                float v = acc[mf][nf][reg] + bias[col];
                if (BF16_OUT)
                    ((ushort*)Cout)[(size_t)row * ldc + col] = f2bf(v);
                else
                    ((float*)Cout)[(size_t)row * ldc + col] = v;
            }
        }
    }
}

// ---------------------------------------------------------------------------
// Sampler. Phase A (lane=point): softmax + trilinear weights -> LDS
//   sm[h][c*32+j] = (coef, byteoff = row*512 + h*128).
// Phase B (lane = corner-subgroup g x channel-block): 16 iters of
//   {LDS b64 read, global dwordx4 gather (8 bf16 ch), 8 fma}; then
//   xor-butterfly over g and float4 stores from lanes 0-7.
// ---------------------------------------------------------------------------
__global__ __launch_bounds__(256) void deform_sample(
    const float* __restrict__ qproj,   // [NQ,512] [off_uv(256)|off_d(128)|attn(128)]
    const ushort* __restrict__ vproj,  // [NV,256] bf16
    const float* __restrict__ ddist,   // [NV,64]
    const float* __restrict__ refpts,  // [NQ,4,3]
    float* __restrict__ out)           // [NQ,256]
{
    const int q    = blockIdx.x;
    const int h    = threadIdx.x >> 6;
    const int lane = threadIdx.x & 63;
    const int j    = lane & 31;

    __shared__ float2 sm[NHEAD][128];

    const float* qrow = qproj + (size_t)q * 512;

    // softmax over 32 logits
    float logit = qrow[384 + h * 32 + j];
    float m = logit;
    #pragma unroll
    for (int o = 16; o; o >>= 1) m = fmaxf(m, __shfl_xor(m, o));
    float e = __expf(logit - m);
    float s = e;
    #pragma unroll
    for (int o = 16; o; o >>= 1) s += __shfl_xor(s, o);
    const float aw = e / s;

    const int l  = j >> 3;
    const int p  = j & 7;
    const int zi = p & 3;
    const int Wl = 160 >> l;
    const int Hl = (l == 0) ? 92 : (l == 1) ? 46 : (l == 2) ? 23 : 12;
    const int st = (l == 0) ? 0  : (l == 1) ? 14720 : (l == 2) ? 18400 : 19320;

    const int oidx = (h * 4 + l) * 8 + p;
    const float ox = qrow[oidx * 2 + 0];
    const float oy = qrow[oidx * 2 + 1];
    const float od = qrow[256 + oidx];
    const float rx = refpts[(q * 4 + zi) * 3 + 0];
    const float ry = refpts[(q * 4 + zi) * 3 + 1];
    const float rz = refpts[(q * 4 + zi) * 3 + 2];

    const float x = fmaf(rx, (float)Wl, ox - 0.5f);
    const float y = fmaf(ry, (float)Hl, oy - 0.5f);
    const float z = fmaf(rz, 64.0f,     od - 0.5f);
    const float x0f = floorf(x), y0f = floorf(y), z0f = floorf(z);
    const float fx = x - x0f, fy = y - y0f, fz = z - z0f;
    const int x0 = (int)x0f, y0 = (int)y0f, z0 = (int)z0f;

    const int z0c = min(max(z0, 0), DEPTHD - 1);
    const int z1c = min(max(z0 + 1, 0), DEPTHD - 1);
    const float wz0 = (z0 >= 0 && z0 <= DEPTHD - 1) ? (1.f - fz) : 0.f;
    const float wz1 = (z0 >= -1 && z0 <= DEPTHD - 2) ? fz : 0.f;

    #pragma unroll
    for (int c = 0; c < 4; ++c) {
        const int   cy = c >> 1, cx = c & 1;
        const int   yi = y0 + cy, xi = x0 + cx;
        const float wy = cy ? fy : (1.f - fy);
        const float wx = cx ? fx : (1.f - fx);
        const bool  valid = (xi >= 0) & (xi < Wl) & (yi >= 0) & (yi < Hl);
        const int   yc = min(max(yi, 0), Hl - 1);
        const int   xc = min(max(xi, 0), Wl - 1);
        const int   row = st + yc * Wl + xc;
        const float* dptr = ddist + (size_t)row * 64;
        const float dscore = wz0 * dptr[z0c] + wz1 * dptr[z1c];
        const float coef = valid ? (aw * wx * wy * dscore) : 0.f;
        if (lane < 32)
            sm[h][c * 32 + j] = make_float2(coef, __int_as_float(row * 512 + h * 128));
    }
    __syncthreads();

    // ---- phase B
    const int g   = lane >> 3;              // corner subgroup 0..7
    const int ch8 = (lane & 7) << 3;        // channel block start within head
    const uint32_t chb = (uint32_t)(ch8 << 1);
    const char* vb = (const char*)vproj;
    const float2* smh = sm[h];

    float acc[8] = {};
    #pragma unroll 8
    for (int t = 0; t < 16; ++t) {
        const float2 wi = smh[t * 8 + g];
        const uint32_t off = (uint32_t)__float_as_int(wi.y) + chb;
        const uint4 raw = *reinterpret_cast<const uint4*>(vb + off);
        const float w = wi.x;
        acc[0] = fmaf(w, bf_lo(raw.x), acc[0]);
        acc[1] = fmaf(w, bf_hi(raw.x), acc[1]);
        acc[2] = fmaf(w, bf_lo(raw.y), acc[2]);
        acc[3] = fmaf(w, bf_hi(raw.y), acc[3]);
        acc[4] = fmaf(w, bf_lo(raw.z), acc[4]);
        acc[5] = fmaf(w, bf_hi(raw.z), acc[5]);
        acc[6] = fmaf(w, bf_lo(raw.w), acc[6]);
        acc[7] = fmaf(w, bf_hi(raw.w), acc[7]);
    }

    #pragma unroll
    for (int o = 8; o <= 32; o <<= 1)
        #pragma unroll
        for (int k = 0; k < 8; ++k)
            acc[k] += __shfl_xor(acc[k], o);

    if (g == 0) {
        float* op = out + (size_t)q * 256 + h * 64 + ch8;
        float4 o0 = make_float4(acc[0], acc[1], acc[2], acc[3]);
        float4 o1 = make_float4(acc[4], acc[5], acc[6], acc[7]);
        *reinterpret_cast<float4*>(op)     = o0;
        *reinterpret_cast<float4*>(op + 4) = o1;
    }
}

// ---------------------------------------------------------------------------
extern "C" void kernel_launch(void* const* d_in, const int* in_sizes, int n_in,
                              void* d_out, int out_size, void* d_ws, size_t ws_size,
                              hipStream_t stream)
{
    const float* query  = (const float*)d_in[0];
    const float* value  = (const float*)d_in[1];
    const float* ddist  = (const float*)d_in[2];
    const float* refpts = (const float*)d_in[3];
    const float* Wv  = (const float*)d_in[6];
    const float* bv  = (const float*)d_in[7];
    const float* Wo  = (const float*)d_in[8];
    const float* bo  = (const float*)d_in[9];
    const float* Wod = (const float*)d_in[10];
    const float* bod = (const float*)d_in[11];
    const float* Wa  = (const float*)d_in[12];
    const float* ba  = (const float*)d_in[13];
    float* out = (float*)d_out;

    char* ws = (char*)d_ws;
    ushort* vbuf = (ushort*)ws;                                   // NV*256 bf16
    float*  qbuf = (float*)(ws + 10014720);                       // NQ*512 f32
    ushort* WvT  = (ushort*)(ws + 10014720 + 40960000);
    ushort* WqT  = WvT + 256 * 256;
    float*  bq   = (float*)(WqT + 512 * 256);

    dim3 blk(256);

    prep_weights<<<dim3(769), blk, 0, stream>>>(Wv, Wo, Wod, Wa, bo, bod, ba, WvT, WqT, bq);

    gemm_mfma_bf16<true><<<dim3(2, (NV + 127) / 128), blk, 0, stream>>>(
        value, WvT, bv, vbuf, NV, 256);

    gemm_mfma_bf16<false><<<dim3(4, (NQ + 127) / 128), blk, 0, stream>>>(
        query, WqT, bq, qbuf, NQ, 512);

    deform_sample<<<dim3(NQ), blk, 0, stream>>>(qbuf, vbuf, ddist, refpts, out);
}

// Round 5
// 152.646 us; speedup vs baseline: 5.0617x; 1.1050x over previous
//
#include <hip/hip_runtime.h>
#include <math.h>

#define NQ    20000
#define NV    19560
#define NHEAD 4
#define DEPTHD 64

typedef __attribute__((ext_vector_type(8))) short short8;
typedef __attribute__((ext_vector_type(4))) float f32x4;

__device__ __forceinline__ ushort f2bf(float f) {
    uint32_t u = __float_as_uint(f);
    uint32_t r = (u + 0x7FFFu + ((u >> 16) & 1u)) >> 16;
    return (ushort)r;
}
__device__ __forceinline__ float bf_lo(uint32_t d) { return __uint_as_float(d << 16); }
__device__ __forceinline__ float bf_hi(uint32_t d) { return __uint_as_float(d & 0xFFFF0000u); }

// ---------------------------------------------------------------------------
// Weight prep: WvT[n][k]=bf16(Wv[k][n]); WqT[n][k]=bf16(concat cols of Wo|Wod|Wa);
// bq = [bo|bod|ba] fp32.
// ---------------------------------------------------------------------------
__global__ __launch_bounds__(256) void prep_weights(
    const float* __restrict__ Wv, const float* __restrict__ Wo,
    const float* __restrict__ Wod, const float* __restrict__ Wa,
    const float* __restrict__ bo, const float* __restrict__ bod,
    const float* __restrict__ ba,
    ushort* __restrict__ WvT, ushort* __restrict__ WqT, float* __restrict__ bq)
{
    const int b = blockIdx.x;
    const int k = threadIdx.x;
    if (b < 256) {
        WvT[b * 256 + k] = f2bf(Wv[k * 256 + b]);
    } else if (b < 768) {
        const int n = b - 256;
        float w;
        if (n < 256)      w = Wo [k * 256 + n];
        else if (n < 384) w = Wod[k * 128 + (n - 256)];
        else              w = Wa [k * 128 + (n - 384)];
        WqT[n * 256 + k] = f2bf(w);
    } else {
        for (int i = k; i < 512; i += 256) {
            float v;
            if (i < 256)      v = bo[i];
            else if (i < 384) v = bod[i - 256];
            else              v = ba[i - 384];
            bq[i] = v;
        }
    }
}

// ---------------------------------------------------------------------------
// bf16 MFMA GEMM: C = A(fp32,[M][256]) x BT(bf16,[N][256])^T + bias.
// ---------------------------------------------------------------------------
template<bool BF16_OUT>
__global__ __launch_bounds__(256) void gemm_mfma_bf16(
    const float* __restrict__ A, const ushort* __restrict__ BT,
    const float* __restrict__ bias, void* __restrict__ Cout,
    int M, int ldc)
{
    constexpr int K = 256, BK = 32;
    __shared__ ushort Asb[128][40];
    __shared__ ushort Bsb[128][40];

    const int tid  = threadIdx.x;
    const int lane = tid & 63;
    const int wave = tid >> 6;
    const int wm   = wave >> 1;
    const int wn   = wave & 1;
    const int brow = blockIdx.y * 128;
    const int bcol = blockIdx.x * 128;
    const int l15  = lane & 15;
    const int kg   = lane >> 4;

    f32x4 acc[4][4] = {};

    const int rA    = tid >> 1;
    const int partA = tid & 1;

    for (int k0 = 0; k0 < K; k0 += BK) {
        {
            ushort tmp[16];
            if (brow + rA < M) {
                const float* ap = A + (size_t)(brow + rA) * K + k0 + partA * 16;
                #pragma unroll
                for (int i = 0; i < 4; ++i) {
                    float4 v = *reinterpret_cast<const float4*>(ap + i * 4);
                    tmp[i * 4 + 0] = f2bf(v.x);
                    tmp[i * 4 + 1] = f2bf(v.y);
                    tmp[i * 4 + 2] = f2bf(v.z);
                    tmp[i * 4 + 3] = f2bf(v.w);
                }
            } else {
                #pragma unroll
                for (int i = 0; i < 16; ++i) tmp[i] = 0;
            }
            *reinterpret_cast<uint4*>(&Asb[rA][partA * 16 + 0]) = *reinterpret_cast<uint4*>(tmp);
            *reinterpret_cast<uint4*>(&Asb[rA][partA * 16 + 8]) = *reinterpret_cast<uint4*>(tmp + 8);
        }
        #pragma unroll
        for (int i = 0; i < 2; ++i) {
            int f  = tid + i * 256;
            int n  = f >> 2;
            int c8 = (f & 3) * 8;
            uint4 v = *reinterpret_cast<const uint4*>(BT + (size_t)(bcol + n) * K + k0 + c8);
            *reinterpret_cast<uint4*>(&Bsb[n][c8]) = v;
        }
        __syncthreads();

        short8 af[4], bfv[4];
        #pragma unroll
        for (int mf = 0; mf < 4; ++mf)
            af[mf] = *reinterpret_cast<const short8*>(&Asb[wm * 64 + mf * 16 + l15][kg * 8]);
        #pragma unroll
        for (int nf = 0; nf < 4; ++nf)
            bfv[nf] = *reinterpret_cast<const short8*>(&Bsb[wn * 64 + nf * 16 + l15][kg * 8]);
        #pragma unroll
        for (int mf = 0; mf < 4; ++mf)
            #pragma unroll
            for (int nf = 0; nf < 4; ++nf)
                acc[mf][nf] = __builtin_amdgcn_mfma_f32_16x16x32_bf16(af[mf], bfv[nf], acc[mf][nf], 0, 0, 0);
        __syncthreads();
    }

    #pragma unroll
    for (int mf = 0; mf < 4; ++mf) {
        #pragma unroll
        for (int reg = 0; reg < 4; ++reg) {
            int row = brow + wm * 64 + mf * 16 + kg * 4 + reg;
            if (row >= M) continue;
            #pragma unroll
            for (int nf = 0; nf < 4; ++nf) {
                int col = bcol + wn * 64 + nf * 16 + l15;
                float v = acc[mf][nf][reg] + bias[col];
                if (BF16_OUT)
                    ((ushort*)Cout)[(size_t)row * ldc + col] = f2bf(v);
                else
                    ((float*)Cout)[(size_t)row * ldc + col] = v;
            }
        }
    }
}

// ---------------------------------------------------------------------------
// Sampler. NO inter-wave communication: sm[h] is written and read only by
// wave h, so no __syncthreads anywhere (wave-internal lgkmcnt ordering).
// Phase A: lane j<32 handles point j corners {0,1}; lane 32+j corners {2,3}.
// Phase B: lane = (corner-subgroup g, channel-block); 16 fully-unrolled
// {LDS b64, global dwordx4, 8 fma} iterations; xor-butterfly; float4 store.
// ---------------------------------------------------------------------------
__global__ __launch_bounds__(256) void deform_sample(
    const float* __restrict__ qproj,   // [NQ,512] [off_uv(256)|off_d(128)|attn(128)]
    const ushort* __restrict__ vproj,  // [NV,256] bf16
    const float* __restrict__ ddist,   // [NV,64]
    const float* __restrict__ refpts,  // [NQ,4,3]
    float* __restrict__ out)           // [NQ,256]
{
    const int q     = blockIdx.x;
    const int h     = threadIdx.x >> 6;
    const int lane  = threadIdx.x & 63;
    const int j     = lane & 31;
    const int chalf = lane >> 5;       // 0: corners 0,1   1: corners 2,3

    __shared__ float2 sm[NHEAD][128];

    const float* qrow = qproj + (size_t)q * 512;

    // softmax over 32 logits (both halves duplicate; xor<32 stays in half)
    float logit = qrow[384 + h * 32 + j];
    float m = logit;
    #pragma unroll
    for (int o = 16; o; o >>= 1) m = fmaxf(m, __shfl_xor(m, o));
    float e = __expf(logit - m);
    float s = e;
    #pragma unroll
    for (int o = 16; o; o >>= 1) s += __shfl_xor(s, o);
    const float aw = e / s;

    const int l  = j >> 3;
    const int p  = j & 7;
    const int zi = p & 3;
    const int Wl = 160 >> l;
    const int Hl = (l == 0) ? 92 : (l == 1) ? 46 : (l == 2) ? 23 : 12;
    const int st = (l == 0) ? 0  : (l == 1) ? 14720 : (l == 2) ? 18400 : 19320;

    const int oidx = (h * 4 + l) * 8 + p;
    const float ox = qrow[oidx * 2 + 0];
    const float oy = qrow[oidx * 2 + 1];
    const float od = qrow[256 + oidx];
    const float rx = refpts[(q * 4 + zi) * 3 + 0];
    const float ry = refpts[(q * 4 + zi) * 3 + 1];
    const float rz = refpts[(q * 4 + zi) * 3 + 2];

    const float x = fmaf(rx, (float)Wl, ox - 0.5f);
    const float y = fmaf(ry, (float)Hl, oy - 0.5f);
    const float z = fmaf(rz, 64.0f,     od - 0.5f);
    const float x0f = floorf(x), y0f = floorf(y), z0f = floorf(z);
    const float fx = x - x0f, fy = y - y0f, fz = z - z0f;
    const int x0 = (int)x0f, y0 = (int)y0f, z0 = (int)z0f;

    const int z0c = min(max(z0, 0), DEPTHD - 1);
    const int z1c = min(max(z0 + 1, 0), DEPTHD - 1);
    const float wz0 = (z0 >= 0 && z0 <= DEPTHD - 1) ? (1.f - fz) : 0.f;
    const float wz1 = (z0 >= -1 && z0 <= DEPTHD - 2) ? fz : 0.f;

    // two corners per lane (upper half takes corners 2,3)
    #pragma unroll
    for (int c2 = 0; c2 < 2; ++c2) {
        const int   c  = chalf * 2 + c2;
        const int   cy = c >> 1, cx = c & 1;
        const int   yi = y0 + cy, xi = x0 + cx;
        const float wy = cy ? fy : (1.f - fy);
        const float wx = cx ? fx : (1.f - fx);
        const bool  valid = (xi >= 0) & (xi < Wl) & (yi >= 0) & (yi < Hl);
        const int   yc = min(max(yi, 0), Hl - 1);
        const int   xc = min(max(xi, 0), Wl - 1);
        const int   row = st + yc * Wl + xc;
        const float* dptr = ddist + (size_t)row * 64;
        const float dscore = wz0 * dptr[z0c] + wz1 * dptr[z1c];
        const float coef = valid ? (aw * wx * wy * dscore) : 0.f;
        sm[h][c * 32 + j] = make_float2(coef, __int_as_float(row * 512 + h * 128));
    }
    // no barrier: wave-private LDS buffer

    // ---- phase B
    const int g   = lane >> 3;              // corner subgroup 0..7
    const int ch8 = (lane & 7) << 3;        // channel block start within head
    const uint32_t chb = (uint32_t)(ch8 << 1);
    const char* vb = (const char*)vproj;
    const float2* smh = sm[h];

    float acc[8] = {};
    #pragma unroll
    for (int t = 0; t < 16; ++t) {
        const float2 wi = smh[t * 8 + g];
        const uint32_t off = (uint32_t)__float_as_int(wi.y) + chb;
        const uint4 raw = *reinterpret_cast<const uint4*>(vb + off);
        const float w = wi.x;
        acc[0] = fmaf(w, bf_lo(raw.x), acc[0]);
        acc[1] = fmaf(w, bf_hi(raw.x), acc[1]);
        acc[2] = fmaf(w, bf_lo(raw.y), acc[2]);
        acc[3] = fmaf(w, bf_hi(raw.y), acc[3]);
        acc[4] = fmaf(w, bf_lo(raw.z), acc[4]);
        acc[5] = fmaf(w, bf_hi(raw.z), acc[5]);
        acc[6] = fmaf(w, bf_lo(raw.w), acc[6]);
        acc[7] = fmaf(w, bf_hi(raw.w), acc[7]);
    }

    #pragma unroll
    for (int o = 8; o <= 32; o <<= 1)
        #pragma unroll
        for (int k = 0; k < 8; ++k)
            acc[k] += __shfl_xor(acc[k], o);

    if (g == 0) {
        float* op = out + (size_t)q * 256 + h * 64 + ch8;
        *reinterpret_cast<float4*>(op)     = make_float4(acc[0], acc[1], acc[2], acc[3]);
        *reinterpret_cast<float4*>(op + 4) = make_float4(acc[4], acc[5], acc[6], acc[7]);
    }
}

// ---------------------------------------------------------------------------
extern "C" void kernel_launch(void* const* d_in, const int* in_sizes, int n_in,
                              void* d_out, int out_size, void* d_ws, size_t ws_size,
                              hipStream_t stream)
{
    const float* query  = (const float*)d_in[0];
    const float* value  = (const float*)d_in[1];
    const float* ddist  = (const float*)d_in[2];
    const float* refpts = (const float*)d_in[3];
    const float* Wv  = (const float*)d_in[6];
    const float* bv  = (const float*)d_in[7];
    const float* Wo  = (const float*)d_in[8];
    const float* bo  = (const float*)d_in[9];
    const float* Wod = (const float*)d_in[10];
    const float* bod = (const float*)d_in[11];
    const float* Wa  = (const float*)d_in[12];
    const float* ba  = (const float*)d_in[13];
    float* out = (float*)d_out;

    char* ws = (char*)d_ws;
    ushort* vbuf = (ushort*)ws;                                   // NV*256 bf16
    float*  qbuf = (float*)(ws + 10014720);                       // NQ*512 f32
    ushort* WvT  = (ushort*)(ws + 10014720 + 40960000);
    ushort* WqT  = WvT + 256 * 256;
    float*  bq   = (float*)(WqT + 512 * 256);

    dim3 blk(256);

    prep_weights<<<dim3(769), blk, 0, stream>>>(Wv, Wo, Wod, Wa, bo, bod, ba, WvT, WqT, bq);

    gemm_mfma_bf16<true><<<dim3(2, (NV + 127) / 128), blk, 0, stream>>>(
        value, WvT, bv, vbuf, NV, 256);

    gemm_mfma_bf16<false><<<dim3(4, (NQ + 127) / 128), blk, 0, stream>>>(
        query, WqT, bq, qbuf, NQ, 512);

    deform_sample<<<dim3(NQ), blk, 0, stream>>>(qbuf, vbuf, ddist, refpts, out);
}